// Round 3
// baseline (620.763 us; speedup 1.0000x reference)
//
#include <hip/hip_runtime.h>

// ---------------------------------------------------------------------------
// GCN 3-layer forward, gather-based CSR, feature-chunked + XCD-pinned agg.
// H buffers are CHUNK-MAJOR: H[c][i][f], c in [0,8), f in [0,16).
// Each 3.2 MB chunk slice fits a 4 MB per-XCD L2; agg blocks are pinned to
// chunk = blockIdx.x & 7 (round-robin block->XCD dispatch) so each XCD's
// gathers stay L2-resident.
// CSR stores only the source id; norm factored as dinv[c]*(sum dinv[r]*v).
//
// d_ws (4-byte units):
//   csr  [E]      int  source ids, grouped by dest
//   A    [N*128]  post-GEMM h (chunk-major)
//   B    [N*128]  layer output (chunk-major)
//   C    [N*16]   layer-3 post-GEMM (row-major)
//   dinv [N]
//   offs [N+1]
//   cnt  [N]      (reused as fill cursor)
//   bsum [256]
// ---------------------------------------------------------------------------

static inline int cdiv(int a, int b) { return (a + b - 1) / b; }

__global__ __launch_bounds__(256) void k_zero_int(int* p, int n) {
    int i = blockIdx.x * 256 + threadIdx.x;
    if (i < n) p[i] = 0;
}

__global__ __launch_bounds__(256) void k_count(const int* __restrict__ col, int* cnt, int e) {
    int i = blockIdx.x * 256 + threadIdx.x;
    if (i < e) atomicAdd(&cnt[col[i]], 1);
}

// per-256-chunk sums for scan; also computes dinv = rsqrt(deg+1)
__global__ __launch_bounds__(256) void k_scanA(const int* __restrict__ cnt, int* bsum,
                                               float* __restrict__ dinv, int n) {
    __shared__ int s[256];
    int t = threadIdx.x;
    int i = blockIdx.x * 256 + t;
    int v = (i < n) ? cnt[i] : 0;
    if (i < n) dinv[i] = rsqrtf((float)(v + 1));
    s[t] = v;
    __syncthreads();
    for (int off = 128; off > 0; off >>= 1) {
        if (t < off) s[t] += s[t + off];
        __syncthreads();
    }
    if (t == 0) bsum[blockIdx.x] = s[0];
}

// exclusive scan of block sums (single block, nb <= 256)
__global__ __launch_bounds__(256) void k_scanB(int* bsum, int nb) {
    __shared__ int s[256];
    int t = threadIdx.x;
    int v = (t < nb) ? bsum[t] : 0;
    s[t] = v;
    for (int off = 1; off < 256; off <<= 1) {
        __syncthreads();
        int x = (t >= off) ? s[t - off] : 0;
        __syncthreads();
        s[t] += x;
    }
    __syncthreads();
    if (t < nb) bsum[t] = s[t] - v;
}

// per-chunk exclusive scan + block offset -> offs; also zeroes cursor (reuse cnt)
__global__ __launch_bounds__(256) void k_scanC(int* __restrict__ cnt, const int* __restrict__ bsum,
                                               int* offs, int n) {
    __shared__ int s[256];
    int t = threadIdx.x;
    int i = blockIdx.x * 256 + t;
    int v = (i < n) ? cnt[i] : 0;
    s[t] = v;
    for (int off = 1; off < 256; off <<= 1) {
        __syncthreads();
        int x = (t >= off) ? s[t - off] : 0;
        __syncthreads();
        s[t] += x;
    }
    __syncthreads();
    if (i <= n) offs[i] = bsum[blockIdx.x] + s[t] - v;
    if (i < n) cnt[i] = 0;   // each i touched by exactly this thread; safe
}

__global__ __launch_bounds__(256) void k_fill(const int* __restrict__ row, const int* __restrict__ col,
                                              const int* __restrict__ offs, int* cur,
                                              int* __restrict__ csr, int e) {
    int i = blockIdx.x * 256 + threadIdx.x;
    if (i >= e) return;
    int c = col[i];
    int pos = offs[c] + atomicAdd(&cur[c], 1);
    csr[pos] = row[i];
}

// H(out, chunk-major)[n,128] = X[n,128] @ W[128,128].
// CM_IN: X is chunk-major; else row-major. 4x4 register blocking.
template <bool CM_IN>
__global__ __launch_bounds__(256) void k_gemm128(const float* __restrict__ X, const float* __restrict__ W,
                                                 float* __restrict__ H, int n) {
    __shared__ float sW[128 * 128];
    __shared__ float sX[32 * 128];
    int tid = threadIdx.x;
    for (int i = tid; i < 4096; i += 256)
        ((float4*)sW)[i] = ((const float4*)W)[i];
    int row0 = blockIdx.x * 32;
    for (int i = tid; i < 1024; i += 256) {
        int r = i >> 5, f4 = i & 31;
        int gr = row0 + r;
        float4 v = make_float4(0.f, 0.f, 0.f, 0.f);
        if (gr < n) {
            size_t idx = CM_IN ? ((size_t)(f4 >> 2) * n * 4 + (size_t)gr * 4 + (f4 & 3))
                               : ((size_t)gr * 32 + f4);
            v = ((const float4*)X)[idx];
        }
        ((float4*)sX)[i] = v;
    }
    __syncthreads();

    int cg = tid & 31, rg = tid >> 5;
    float acc[4][4];
    #pragma unroll
    for (int i = 0; i < 4; ++i)
        #pragma unroll
        for (int j = 0; j < 4; ++j) acc[i][j] = 0.f;

    #pragma unroll 4
    for (int k = 0; k < 128; ++k) {
        float4 w4 = ((const float4*)sW)[k * 32 + cg];
        #pragma unroll
        for (int i = 0; i < 4; ++i) {
            float xv = sX[(rg * 4 + i) * 128 + k];
            acc[i][0] = fmaf(xv, w4.x, acc[i][0]);
            acc[i][1] = fmaf(xv, w4.y, acc[i][1]);
            acc[i][2] = fmaf(xv, w4.z, acc[i][2]);
            acc[i][3] = fmaf(xv, w4.w, acc[i][3]);
        }
    }
    // write chunk-major: thread's 4 cols = cg*4..+3 all inside chunk cg>>2
    int chunk = cg >> 2, w4i = cg & 3;
    #pragma unroll
    for (int i = 0; i < 4; ++i) {
        int gr = row0 + rg * 4 + i;
        if (gr < n)
            ((float4*)H)[(size_t)chunk * n * 4 + (size_t)gr * 4 + w4i] =
                make_float4(acc[i][0], acc[i][1], acc[i][2], acc[i][3]);
    }
}

// C(row-major)[n,16] = X(chunk-major)[n,128] @ W[128,16].
__global__ __launch_bounds__(256) void k_gemm16(const float* __restrict__ X, const float* __restrict__ W,
                                                float* __restrict__ H, int n) {
    __shared__ float sX[16 * 132];
    __shared__ float sW[128 * 16];
    int tid = threadIdx.x;
    for (int i = tid; i < 512; i += 256)
        ((float4*)sW)[i] = ((const float4*)W)[i];
    int row0 = blockIdx.x * 16;
    for (int i = tid; i < 512; i += 256) {
        int r = i >> 5, f4 = i & 31;
        int gr = row0 + r;
        float4 v = make_float4(0.f, 0.f, 0.f, 0.f);
        if (gr < n)
            v = ((const float4*)X)[(size_t)(f4 >> 2) * n * 4 + (size_t)gr * 4 + (f4 & 3)];
        *(float4*)&sX[r * 132 + f4 * 4] = v;
    }
    __syncthreads();

    int rl = tid >> 4, cj = tid & 15;
    float acc = 0.f;
    #pragma unroll 8
    for (int k = 0; k < 128; ++k)
        acc = fmaf(sX[rl * 132 + k], sW[k * 16 + cj], acc);
    int gr = row0 + rl;
    if (gr < n) H[(size_t)gr * 16 + cj] = acc;
}

// Gather-aggregate over one 16-feature chunk, chunk pinned per XCD.
// out[c][i][:] = relu( dinv[i]*( sum_e dinv[r]*H[c][r][:] + dinv[i]*H[c][i][:] ) + b[c*16..] )
__global__ __launch_bounds__(256) void k_agg128_cm(const float* __restrict__ H, const int* __restrict__ csr,
                                                   const int* __restrict__ offs, const float* __restrict__ dinv,
                                                   const float* __restrict__ b, float* __restrict__ out, int n) {
    int chunk = blockIdx.x & 7;           // round-robin -> XCD pin
    int t = (blockIdx.x >> 3) * 256 + threadIdx.x;
    int node = t >> 2;
    if (node >= n) return;
    int sub = t & 3;
    const float* Hc = H + (size_t)chunk * n * 16;
    int ed = offs[node], end = offs[node + 1];
    float4 acc = make_float4(0.f, 0.f, 0.f, 0.f);
    for (; ed + 1 < end; ed += 2) {
        int r0 = csr[ed], r1 = csr[ed + 1];
        float w0 = dinv[r0], w1 = dinv[r1];
        float4 v0 = ((const float4*)(Hc + (size_t)r0 * 16))[sub];
        float4 v1 = ((const float4*)(Hc + (size_t)r1 * 16))[sub];
        acc.x = fmaf(w0, v0.x, acc.x); acc.y = fmaf(w0, v0.y, acc.y);
        acc.z = fmaf(w0, v0.z, acc.z); acc.w = fmaf(w0, v0.w, acc.w);
        acc.x = fmaf(w1, v1.x, acc.x); acc.y = fmaf(w1, v1.y, acc.y);
        acc.z = fmaf(w1, v1.z, acc.z); acc.w = fmaf(w1, v1.w, acc.w);
    }
    if (ed < end) {
        int r0 = csr[ed];
        float w0 = dinv[r0];
        float4 v0 = ((const float4*)(Hc + (size_t)r0 * 16))[sub];
        acc.x = fmaf(w0, v0.x, acc.x); acc.y = fmaf(w0, v0.y, acc.y);
        acc.z = fmaf(w0, v0.z, acc.z); acc.w = fmaf(w0, v0.w, acc.w);
    }
    float dc = dinv[node];
    float4 hv = ((const float4*)(Hc + (size_t)node * 16))[sub];
    float4 bv = ((const float4*)(b + chunk * 16))[sub];
    float4 o;
    o.x = fmaxf(fmaf(dc, fmaf(dc, hv.x, acc.x), bv.x), 0.f);
    o.y = fmaxf(fmaf(dc, fmaf(dc, hv.y, acc.y), bv.y), 0.f);
    o.z = fmaxf(fmaf(dc, fmaf(dc, hv.z, acc.z), bv.z), 0.f);
    o.w = fmaxf(fmaf(dc, fmaf(dc, hv.w, acc.w), bv.w), 0.f);
    ((float4*)(out + (size_t)chunk * n * 16 + (size_t)node * 16))[sub] = o;
}

// F=16 gather-aggregate (layer 3, row-major, 3.2 MB source fits every L2).
__global__ __launch_bounds__(256) void k_agg16(const float* __restrict__ H, const int* __restrict__ csr,
                                               const int* __restrict__ offs, const float* __restrict__ dinv,
                                               const float* __restrict__ b, float* __restrict__ out, int n) {
    int t = blockIdx.x * 256 + threadIdx.x;
    int node = t >> 2;
    if (node >= n) return;
    int sub = t & 3;
    int ed = offs[node], end = offs[node + 1];
    float4 acc = make_float4(0.f, 0.f, 0.f, 0.f);
    for (; ed + 1 < end; ed += 2) {
        int r0 = csr[ed], r1 = csr[ed + 1];
        float w0 = dinv[r0], w1 = dinv[r1];
        float4 v0 = ((const float4*)(H + (size_t)r0 * 16))[sub];
        float4 v1 = ((const float4*)(H + (size_t)r1 * 16))[sub];
        acc.x = fmaf(w0, v0.x, acc.x); acc.y = fmaf(w0, v0.y, acc.y);
        acc.z = fmaf(w0, v0.z, acc.z); acc.w = fmaf(w0, v0.w, acc.w);
        acc.x = fmaf(w1, v1.x, acc.x); acc.y = fmaf(w1, v1.y, acc.y);
        acc.z = fmaf(w1, v1.z, acc.z); acc.w = fmaf(w1, v1.w, acc.w);
    }
    if (ed < end) {
        int r0 = csr[ed];
        float w0 = dinv[r0];
        float4 v0 = ((const float4*)(H + (size_t)r0 * 16))[sub];
        acc.x = fmaf(w0, v0.x, acc.x); acc.y = fmaf(w0, v0.y, acc.y);
        acc.z = fmaf(w0, v0.z, acc.z); acc.w = fmaf(w0, v0.w, acc.w);
    }
    float dc = dinv[node];
    float4 hv = ((const float4*)(H + (size_t)node * 16))[sub];
    float4 bv = ((const float4*)b)[sub];
    float4 o;
    o.x = fmaxf(fmaf(dc, fmaf(dc, hv.x, acc.x), bv.x), 0.f);
    o.y = fmaxf(fmaf(dc, fmaf(dc, hv.y, acc.y), bv.y), 0.f);
    o.z = fmaxf(fmaf(dc, fmaf(dc, hv.z, acc.z), bv.z), 0.f);
    o.w = fmaxf(fmaf(dc, fmaf(dc, hv.w, acc.w), bv.w), 0.f);
    ((float4*)(out + (size_t)node * 16))[sub] = o;
}

extern "C" void kernel_launch(void* const* d_in, const int* in_sizes, int n_in,
                              void* d_out, int out_size, void* d_ws, size_t ws_size,
                              hipStream_t stream) {
    const float* x  = (const float*)d_in[0];
    const int*   ei = (const int*)d_in[1];
    const float* W1 = (const float*)d_in[2];
    const float* b1 = (const float*)d_in[3];
    const float* W2 = (const float*)d_in[4];
    const float* b2 = (const float*)d_in[5];
    const float* W3 = (const float*)d_in[6];
    const float* b3 = (const float*)d_in[7];

    const int n = in_sizes[0] / 128;
    const int e = in_sizes[1] / 2;
    const int* row = ei;       // source j
    const int* col = ei + e;   // target i

    int*   csr  = (int*)d_ws;
    float* A    = (float*)(csr + e);
    float* B    = A + (size_t)n * 128;
    float* C    = B + (size_t)n * 128;
    float* dinv = C + (size_t)n * 16;
    int*   offs = (int*)(dinv + n);
    int*   cnt  = offs + (n + 1);
    int*   bsum = cnt + n;
    float* out  = (float*)d_out;

    const int nb = cdiv(n + 1, 256);

    // --- CSR build ---
    k_zero_int<<<cdiv(n, 256), 256, 0, stream>>>(cnt, n);
    k_count   <<<cdiv(e, 256), 256, 0, stream>>>(col, cnt, e);
    k_scanA   <<<nb, 256, 0, stream>>>(cnt, bsum, dinv, n);
    k_scanB   <<<1, 256, 0, stream>>>(bsum, nb);
    k_scanC   <<<nb, 256, 0, stream>>>(cnt, bsum, offs, n);
    k_fill    <<<cdiv(e, 256), 256, 0, stream>>>(row, col, offs, cnt, csr, e);

    const int aggGrid = 8 * cdiv(n * 4, 256);

    // --- layer 1 ---
    k_gemm128<false><<<cdiv(n, 32), 256, 0, stream>>>(x, W1, A, n);
    k_agg128_cm<<<aggGrid, 256, 0, stream>>>(A, csr, offs, dinv, b1, B, n);
    // --- layer 2 ---
    k_gemm128<true><<<cdiv(n, 32), 256, 0, stream>>>(B, W2, A, n);
    k_agg128_cm<<<aggGrid, 256, 0, stream>>>(A, csr, offs, dinv, b2, B, n);
    // --- layer 3 ---
    k_gemm16 <<<cdiv(n, 16), 256, 0, stream>>>(B, W3, C, n);
    k_agg16  <<<cdiv(n * 4, 256), 256, 0, stream>>>(C, csr, offs, dinv, b3, out, n);
}

// Round 4
// 481.964 us; speedup vs baseline: 1.2880x; 1.2880x over previous
//
#include <hip/hip_runtime.h>

// ---------------------------------------------------------------------------
// GCN 3-layer forward, gather-based CSR (row-major H everywhere).
// Aggregation: one wave per node; 32 lanes span the 128-f row (float4/lane);
// wave halves process even/odd edges; 4-pair unroll = 8 edges in flight.
// CSR entries are int2 (source row, norm bits) -> one broadcast 8B load/edge.
//
// d_ws (4-byte units):
//   csr  [2*E]   int2 (row, norm)
//   A    [N*128] post-GEMM h
//   B    [N*128] layer output
//   C    [N*16]  layer-3 post-GEMM
//   dinv [N]
//   offs [N+1]
//   cnt  [N]     (reused as fill cursor)
//   bsum [256]
// ---------------------------------------------------------------------------

static inline int cdiv(int a, int b) { return (a + b - 1) / b; }

__global__ __launch_bounds__(256) void k_zero_int(int* p, int n) {
    int i = blockIdx.x * 256 + threadIdx.x;
    if (i < n) p[i] = 0;
}

__global__ __launch_bounds__(256) void k_count(const int* __restrict__ col, int* cnt, int e) {
    int i = blockIdx.x * 256 + threadIdx.x;
    if (i < e) atomicAdd(&cnt[col[i]], 1);
}

// per-256-chunk sums for scan; also computes dinv = rsqrt(deg+1)
__global__ __launch_bounds__(256) void k_scanA(const int* __restrict__ cnt, int* bsum,
                                               float* __restrict__ dinv, int n) {
    __shared__ int s[256];
    int t = threadIdx.x;
    int i = blockIdx.x * 256 + t;
    int v = (i < n) ? cnt[i] : 0;
    if (i < n) dinv[i] = rsqrtf((float)(v + 1));
    s[t] = v;
    __syncthreads();
    for (int off = 128; off > 0; off >>= 1) {
        if (t < off) s[t] += s[t + off];
        __syncthreads();
    }
    if (t == 0) bsum[blockIdx.x] = s[0];
}

__global__ __launch_bounds__(256) void k_scanB(int* bsum, int nb) {
    __shared__ int s[256];
    int t = threadIdx.x;
    int v = (t < nb) ? bsum[t] : 0;
    s[t] = v;
    for (int off = 1; off < 256; off <<= 1) {
        __syncthreads();
        int x = (t >= off) ? s[t - off] : 0;
        __syncthreads();
        s[t] += x;
    }
    __syncthreads();
    if (t < nb) bsum[t] = s[t] - v;
}

// per-chunk exclusive scan + block offset -> offs; also zeroes cursor (reuse cnt)
__global__ __launch_bounds__(256) void k_scanC(int* __restrict__ cnt, const int* __restrict__ bsum,
                                               int* offs, int n) {
    __shared__ int s[256];
    int t = threadIdx.x;
    int i = blockIdx.x * 256 + t;
    int v = (i < n) ? cnt[i] : 0;
    s[t] = v;
    for (int off = 1; off < 256; off <<= 1) {
        __syncthreads();
        int x = (t >= off) ? s[t - off] : 0;
        __syncthreads();
        s[t] += x;
    }
    __syncthreads();
    if (i <= n) offs[i] = bsum[blockIdx.x] + s[t] - v;
    if (i < n) cnt[i] = 0;
}

__global__ __launch_bounds__(256) void k_fill(const int* __restrict__ row, const int* __restrict__ col,
                                              const float* __restrict__ dinv, const int* __restrict__ offs,
                                              int* cur, int2* __restrict__ csr, int e) {
    int i = blockIdx.x * 256 + threadIdx.x;
    if (i >= e) return;
    int c = col[i], r = row[i];
    float w = dinv[r] * dinv[c];
    int pos = offs[c] + atomicAdd(&cur[c], 1);
    csr[pos] = make_int2(r, __float_as_int(w));
}

// H[n,128] = X[n,128] @ W[128,128]; W + 32-row tile in LDS, 4x4 reg blocking.
__global__ __launch_bounds__(256) void k_gemm128(const float* __restrict__ X, const float* __restrict__ W,
                                                 float* __restrict__ H, int n) {
    __shared__ float sW[128 * 128];
    __shared__ float sX[32 * 128];
    int tid = threadIdx.x;
    for (int i = tid; i < 4096; i += 256)
        ((float4*)sW)[i] = ((const float4*)W)[i];
    int row0 = blockIdx.x * 32;
    for (int i = tid; i < 1024; i += 256) {
        int gr = row0 + (i >> 5);
        ((float4*)sX)[i] = (gr < n) ? ((const float4*)X)[(size_t)gr * 32 + (i & 31)]
                                    : make_float4(0.f, 0.f, 0.f, 0.f);
    }
    __syncthreads();

    int cg = tid & 31, rg = tid >> 5;
    float acc[4][4];
    #pragma unroll
    for (int i = 0; i < 4; ++i)
        #pragma unroll
        for (int j = 0; j < 4; ++j) acc[i][j] = 0.f;

    #pragma unroll 4
    for (int k = 0; k < 128; ++k) {
        float4 w4 = ((const float4*)sW)[k * 32 + cg];
        #pragma unroll
        for (int i = 0; i < 4; ++i) {
            float xv = sX[(rg * 4 + i) * 128 + k];
            acc[i][0] = fmaf(xv, w4.x, acc[i][0]);
            acc[i][1] = fmaf(xv, w4.y, acc[i][1]);
            acc[i][2] = fmaf(xv, w4.z, acc[i][2]);
            acc[i][3] = fmaf(xv, w4.w, acc[i][3]);
        }
    }
    #pragma unroll
    for (int i = 0; i < 4; ++i) {
        int gr = row0 + rg * 4 + i;
        if (gr < n)
            ((float4*)H)[(size_t)gr * 32 + cg] =
                make_float4(acc[i][0], acc[i][1], acc[i][2], acc[i][3]);
    }
}

// C[n,16] = X[n,128] @ W[128,16].
__global__ __launch_bounds__(256) void k_gemm16(const float* __restrict__ X, const float* __restrict__ W,
                                                float* __restrict__ H, int n) {
    __shared__ float sX[16 * 132];
    __shared__ float sW[128 * 16];
    int tid = threadIdx.x;
    for (int i = tid; i < 512; i += 256)
        ((float4*)sW)[i] = ((const float4*)W)[i];
    int row0 = blockIdx.x * 16;
    for (int i = tid; i < 512; i += 256) {
        int r = i >> 5, c = i & 31;
        int gr = row0 + r;
        float4 v = (gr < n) ? ((const float4*)X)[(size_t)gr * 32 + c]
                            : make_float4(0.f, 0.f, 0.f, 0.f);
        *(float4*)&sX[r * 132 + c * 4] = v;
    }
    __syncthreads();

    int rl = tid >> 4, cj = tid & 15;
    float acc = 0.f;
    #pragma unroll 8
    for (int k = 0; k < 128; ++k)
        acc = fmaf(sX[rl * 132 + k], sW[k * 16 + cj], acc);
    int gr = row0 + rl;
    if (gr < n) H[(size_t)gr * 16 + cj] = acc;
}

// F=128 gather-aggregate: wave per node, float4/lane, even/odd edge halves,
// 4-pair unroll (8 edges in flight). out = relu(agg + dinv^2*h + b).
__global__ __launch_bounds__(256) void k_agg128(const float* __restrict__ H, const int2* __restrict__ csr,
                                                const int* __restrict__ offs, const float* __restrict__ dinv,
                                                const float* __restrict__ b, float* __restrict__ out, int n) {
    int node = (blockIdx.x * 256 + threadIdx.x) >> 6;
    if (node >= n) return;
    int lane = threadIdx.x & 63;
    int sub  = lane & 31;     // float4 index within the 128-f row
    int half = lane >> 5;     // 0: even edges, 1: odd edges
    const float4* H4 = (const float4*)H;
    int ed = offs[node], end = offs[node + 1];
    float4 acc = make_float4(0.f, 0.f, 0.f, 0.f);

    for (; ed + 7 < end; ed += 8) {
        int2 p0 = csr[ed     + half];
        int2 p1 = csr[ed + 2 + half];
        int2 p2 = csr[ed + 4 + half];
        int2 p3 = csr[ed + 6 + half];
        float4 v0 = H4[(size_t)p0.x * 32 + sub];
        float4 v1 = H4[(size_t)p1.x * 32 + sub];
        float4 v2 = H4[(size_t)p2.x * 32 + sub];
        float4 v3 = H4[(size_t)p3.x * 32 + sub];
        float w0 = __int_as_float(p0.y), w1 = __int_as_float(p1.y);
        float w2 = __int_as_float(p2.y), w3 = __int_as_float(p3.y);
        acc.x = fmaf(w0, v0.x, acc.x); acc.y = fmaf(w0, v0.y, acc.y);
        acc.z = fmaf(w0, v0.z, acc.z); acc.w = fmaf(w0, v0.w, acc.w);
        acc.x = fmaf(w1, v1.x, acc.x); acc.y = fmaf(w1, v1.y, acc.y);
        acc.z = fmaf(w1, v1.z, acc.z); acc.w = fmaf(w1, v1.w, acc.w);
        acc.x = fmaf(w2, v2.x, acc.x); acc.y = fmaf(w2, v2.y, acc.y);
        acc.z = fmaf(w2, v2.z, acc.z); acc.w = fmaf(w2, v2.w, acc.w);
        acc.x = fmaf(w3, v3.x, acc.x); acc.y = fmaf(w3, v3.y, acc.y);
        acc.z = fmaf(w3, v3.z, acc.z); acc.w = fmaf(w3, v3.w, acc.w);
    }
    #pragma unroll
    for (int s = 0; s < 4; ++s) {          // tail: up to 7 edges
        int idx = ed + 2 * s + half;
        if (idx < end) {
            int2 p = csr[idx];
            float4 v = H4[(size_t)p.x * 32 + sub];
            float w = __int_as_float(p.y);
            acc.x = fmaf(w, v.x, acc.x); acc.y = fmaf(w, v.y, acc.y);
            acc.z = fmaf(w, v.z, acc.z); acc.w = fmaf(w, v.w, acc.w);
        }
    }
    // combine even/odd halves (lane ^ 32)
    acc.x += __shfl_xor(acc.x, 32);
    acc.y += __shfl_xor(acc.y, 32);
    acc.z += __shfl_xor(acc.z, 32);
    acc.w += __shfl_xor(acc.w, 32);

    float di = dinv[node], sl = di * di;
    float4 hv = H4[(size_t)node * 32 + sub];
    float4 bv = ((const float4*)b)[sub];
    float4 o;
    o.x = fmaxf(fmaf(sl, hv.x, acc.x) + bv.x, 0.f);
    o.y = fmaxf(fmaf(sl, hv.y, acc.y) + bv.y, 0.f);
    o.z = fmaxf(fmaf(sl, hv.z, acc.z) + bv.z, 0.f);
    o.w = fmaxf(fmaf(sl, hv.w, acc.w) + bv.w, 0.f);
    if (half == 0)
        ((float4*)out)[(size_t)node * 32 + sub] = o;
}

// F=16 gather-aggregate: 8 lanes per node (4 span row, even/odd halves).
__global__ __launch_bounds__(256) void k_agg16(const float* __restrict__ H, const int2* __restrict__ csr,
                                               const int* __restrict__ offs, const float* __restrict__ dinv,
                                               const float* __restrict__ b, float* __restrict__ out, int n) {
    int t = blockIdx.x * 256 + threadIdx.x;
    int node = t >> 3;
    if (node >= n) return;
    int lane = t & 7;
    int sub  = lane & 3;
    int half = lane >> 2;
    const float4* H4 = (const float4*)H;
    int ed = offs[node], end = offs[node + 1];
    float4 acc = make_float4(0.f, 0.f, 0.f, 0.f);

    for (; ed + 3 < end; ed += 4) {
        int2 p0 = csr[ed     + half];
        int2 p1 = csr[ed + 2 + half];
        float4 v0 = H4[(size_t)p0.x * 4 + sub];
        float4 v1 = H4[(size_t)p1.x * 4 + sub];
        float w0 = __int_as_float(p0.y), w1 = __int_as_float(p1.y);
        acc.x = fmaf(w0, v0.x, acc.x); acc.y = fmaf(w0, v0.y, acc.y);
        acc.z = fmaf(w0, v0.z, acc.z); acc.w = fmaf(w0, v0.w, acc.w);
        acc.x = fmaf(w1, v1.x, acc.x); acc.y = fmaf(w1, v1.y, acc.y);
        acc.z = fmaf(w1, v1.z, acc.z); acc.w = fmaf(w1, v1.w, acc.w);
    }
    #pragma unroll
    for (int s = 0; s < 2; ++s) {          // tail: up to 3 edges
        int idx = ed + 2 * s + half;
        if (idx < end) {
            int2 p = csr[idx];
            float4 v = H4[(size_t)p.x * 4 + sub];
            float w = __int_as_float(p.y);
            acc.x = fmaf(w, v.x, acc.x); acc.y = fmaf(w, v.y, acc.y);
            acc.z = fmaf(w, v.z, acc.z); acc.w = fmaf(w, v.w, acc.w);
        }
    }
    acc.x += __shfl_xor(acc.x, 4);
    acc.y += __shfl_xor(acc.y, 4);
    acc.z += __shfl_xor(acc.z, 4);
    acc.w += __shfl_xor(acc.w, 4);

    float di = dinv[node], sl = di * di;
    float4 hv = H4[(size_t)node * 4 + sub];
    float4 bv = ((const float4*)b)[sub];
    float4 o;
    o.x = fmaxf(fmaf(sl, hv.x, acc.x) + bv.x, 0.f);
    o.y = fmaxf(fmaf(sl, hv.y, acc.y) + bv.y, 0.f);
    o.z = fmaxf(fmaf(sl, hv.z, acc.z) + bv.z, 0.f);
    o.w = fmaxf(fmaf(sl, hv.w, acc.w) + bv.w, 0.f);
    if (half == 0)
        ((float4*)out)[(size_t)node * 4 + sub] = o;
}

extern "C" void kernel_launch(void* const* d_in, const int* in_sizes, int n_in,
                              void* d_out, int out_size, void* d_ws, size_t ws_size,
                              hipStream_t stream) {
    const float* x  = (const float*)d_in[0];
    const int*   ei = (const int*)d_in[1];
    const float* W1 = (const float*)d_in[2];
    const float* b1 = (const float*)d_in[3];
    const float* W2 = (const float*)d_in[4];
    const float* b2 = (const float*)d_in[5];
    const float* W3 = (const float*)d_in[6];
    const float* b3 = (const float*)d_in[7];

    const int n = in_sizes[0] / 128;
    const int e = in_sizes[1] / 2;
    const int* row = ei;       // source j
    const int* col = ei + e;   // target i

    int2*  csr  = (int2*)d_ws;
    float* A    = (float*)(csr + e);
    float* B    = A + (size_t)n * 128;
    float* C    = B + (size_t)n * 128;
    float* dinv = C + (size_t)n * 16;
    int*   offs = (int*)(dinv + n);
    int*   cnt  = offs + (n + 1);
    int*   bsum = cnt + n;
    float* out  = (float*)d_out;

    const int nb = cdiv(n + 1, 256);

    // --- CSR build ---
    k_zero_int<<<cdiv(n, 256), 256, 0, stream>>>(cnt, n);
    k_count   <<<cdiv(e, 256), 256, 0, stream>>>(col, cnt, e);
    k_scanA   <<<nb, 256, 0, stream>>>(cnt, bsum, dinv, n);
    k_scanB   <<<1, 256, 0, stream>>>(bsum, nb);
    k_scanC   <<<nb, 256, 0, stream>>>(cnt, bsum, offs, n);
    k_fill    <<<cdiv(e, 256), 256, 0, stream>>>(row, col, dinv, offs, cnt, csr, e);

    // --- layer 1 ---
    k_gemm128<<<cdiv(n, 32), 256, 0, stream>>>(x, W1, A, n);
    k_agg128 <<<cdiv(n * 64, 256), 256, 0, stream>>>(A, csr, offs, dinv, b1, B, n);
    // --- layer 2 ---
    k_gemm128<<<cdiv(n, 32), 256, 0, stream>>>(B, W2, A, n);
    k_agg128 <<<cdiv(n * 64, 256), 256, 0, stream>>>(A, csr, offs, dinv, b2, B, n);
    // --- layer 3 ---
    k_gemm16 <<<cdiv(n, 16), 256, 0, stream>>>(B, W3, C, n);
    k_agg16  <<<cdiv(n * 8, 256), 256, 0, stream>>>(C, csr, offs, dinv, b3, out, n);
}